// Round 14
// baseline (798.957 us; speedup 1.0000x reference)
//
#include <hip/hip_runtime.h>
#include <hip/hip_bf16.h>
#include <math.h>

// Problem constants (fixed by reference)
constexpr int T_ = 16384;
constexpr int D_ = 2048;   // hidden
constexpr int H_ = 1024;   // intermediate
constexpr int E_ = 8;

constexpr int BM = 128, BK = 64;
constexpr int MT128 = T_ / 128 + E_;    // 136 worst-case m-tiles
constexpr int NT16  = 16;               // n-tiles (N = 2048 / 128), both stages
constexpr int NGEMM = MT128 * NT16;     // 2176, % 8 == 0

constexpr int NW2   = 512;              // w2 f32->bf16 conversion tasks
constexpr int NTASK = NW2 + 2 * NGEMM;  // 4864
constexpr int PERS  = 768;              // persistent blocks: 3/CU (capacity 4) -> resident

typedef __bf16 bf16x8 __attribute__((ext_vector_type(8)));
typedef float  f32x4  __attribute__((ext_vector_type(4)));

__device__ __forceinline__ int imin(int a, int b) { return a < b ? a : b; }

__device__ __forceinline__ bf16x8 cvt8(const float* p) {
    float4 u = *reinterpret_cast<const float4*>(p);
    float4 v = *reinterpret_cast<const float4*>(p + 4);
    bf16x8 r;
    r[0] = (__bf16)u.x; r[1] = (__bf16)u.y; r[2] = (__bf16)u.z; r[3] = (__bf16)u.w;
    r[4] = (__bf16)v.x; r[5] = (__bf16)v.y; r[6] = (__bf16)v.z; r[7] = (__bf16)v.w;
    return r;
}

// ---- 128x64 bf16 tile in LDS: 128B-pitch rows, XOR swizzle ((row&7)<<4).
// Measured SQ_LDS_BANK_CONFLICT == 0 (rounds 1-2, 9, 10, 13). VERBATIM.
__device__ __forceinline__ bf16x8 ld_lds8(const char* lds, int row, int kbyte) {
    int byte = row * 128 + (kbyte ^ ((row & 7) << 4));
    return *reinterpret_cast<const bf16x8*>(lds + byte);
}

// stage a 128x64 bf16 tile -> LDS via global_load_lds w=16, source pre-swizzled
// (VERBATIM round-13; 4 glds/thread, 16 chunks of 1KB).
template<int K_>
__device__ __forceinline__ void stage_glds(char* lds, const __bf16* __restrict__ src,
                                           int valid, int tid) {
    int wave = tid >> 6, l = tid & 63;
#pragma unroll
    for (int i = 0; i < 4; ++i) {
        int chunk = wave * 4 + i;            // 0..15, 1KB each
        int row = chunk * 8 + (l >> 3);      // LDS dest row (lane-implicit)
        int rc = imin(row, valid - 1);       // clamp source row for partial tiles
        int colb = ((l & 7) * 16) ^ ((row & 7) << 4);   // pre-swizzled source col
        const char* gp = reinterpret_cast<const char*>(src)
                       + (size_t)rc * (K_ * 2) + colb;
        __builtin_amdgcn_global_load_lds(
            (const __attribute__((address_space(1))) void*)gp,
            (__attribute__((address_space(3))) void*)(lds + chunk * 1024), 16, 0, 0);
    }
}

// expert lookup for BM=128 tiles (round-1 verbatim)
__device__ __forceinline__ bool find_expert(const int* __restrict__ counts, int mt,
                                            int& e, int& row0, int& valid) {
    int macc = 0, start = 0;
    e = -1;
    for (int i = 0; i < E_; ++i) {
        int c = counts[i];
        int t = (c + BM - 1) >> 7;
        if (e < 0 && mt < macc + t) {
            int lm = mt - macc;
            e = i; row0 = start + lm * BM; valid = imin(BM, c - lm * BM);
        }
        macc += t; start += c;
    }
    return e >= 0;
}

// -------- r13-verified 128x128 tile body (m97 structure), shared by all paths --------
template<int K_, bool FUSE>
__device__ __forceinline__ void gemm_body(char* sA, char* sB, int tid,
        int nt, int e, int row0, int valid,
        const __bf16* __restrict__ A, const __bf16* __restrict__ Bw,
        __bf16* __restrict__ hout, float* __restrict__ fout) {
    int wid = tid >> 6, lane = tid & 63;
    int wr = wid >> 1, wc = wid & 1;          // 2M x 2N
    int frow = lane & 15, fkb = (lane >> 4) * 16;

    const __bf16* Ab = A  + (size_t)row0 * K_;
    const __bf16* Bb = Bw + (size_t)e * 2048 * K_ + (size_t)(nt * 128) * K_;

    f32x4 acc[4][4] = {};

    for (int k0 = 0; k0 < K_; k0 += BK) {
        stage_glds<K_>(sA, Ab + k0, valid, tid);
        stage_glds<K_>(sB, Bb + k0, 128, tid);
        __syncthreads();
#pragma unroll
        for (int kk = 0; kk < BK; kk += 32) {
            int kb = kk * 2 + fkb;
            bf16x8 a[4], b[4];
#pragma unroll
            for (int m = 0; m < 4; ++m) a[m] = ld_lds8(sA, wr * 64 + m * 16 + frow, kb);
#pragma unroll
            for (int n = 0; n < 4; ++n) b[n] = ld_lds8(sB, wc * 64 + n * 16 + frow, kb);
#pragma unroll
            for (int m = 0; m < 4; ++m)
#pragma unroll
                for (int n = 0; n < 4; ++n)
                    acc[m][n] = __builtin_amdgcn_mfma_f32_16x16x32_bf16(a[m], b[n], acc[m][n], 0, 0, 0);
        }
        __syncthreads();
    }

    int q = lane >> 4;
#pragma unroll
    for (int m = 0; m < 4; ++m)
#pragma unroll
        for (int j = 0; j < 4; ++j) {
            int lrow = wr * 64 + m * 16 + q * 4 + j;
            if (lrow < valid) {
                size_t rg = (size_t)(row0 + lrow);
                if (FUSE) {
                    // wb rows interleaved in 32-row groups (16 w1 + 16 w3):
                    // n even -> w1 (c1), n odd -> w3 (c3), same h column.
#pragma unroll
                    for (int p = 0; p < 2; ++p) {
                        float c1 = acc[m][2 * p][j], c3 = acc[m][2 * p + 1][j];
                        float inner = 0.7978845608028654f * (c1 + 0.044715f * c1 * c1 * c1);
                        float g = 0.5f * c1 * (1.0f + tanhf(inner));
                        int col = nt * 64 + wc * 32 + p * 16 + frow;
                        hout[rg * H_ + col] = (__bf16)(g * c3);
                    }
                } else {
#pragma unroll
                    for (int n = 0; n < 4; ++n) {
                        int col = nt * 128 + wc * 64 + n * 16 + frow;
                        fout[rg * D_ + col] = acc[m][n][j];
                    }
                }
            }
        }
}

// ============== round-14: persistent fused {w2cvt | stage1 | stage2} ==============
// 768 blocks (3/CU, capacity 4 -> all resident). Block b takes tasks b, b+768, ...
// (stride % 8 == 0 -> block's tasks share one XCD -> r10 L2 swizzle preserved).
// Queue: [0,512) w2cvt | [512,2688) stage1 | [2688,4864) stage2.
// Gates: stage2(mt) spins on cnt[mt]==16 and w2done==512 (device-scope atomics,
// release = threadfence+barrier+atomicAdd, acquire = spin+threadfence).
// No deadlock: every block's indices increase, so a block owning a pending
// producer task is at a gate-free task -> progress.
__global__ __launch_bounds__(256, 4) void ffn_fused(
        const __bf16* __restrict__ xb, const __bf16* __restrict__ wb,
        __bf16* __restrict__ w2b, const float* __restrict__ w2,
        const int* __restrict__ counts,
        __bf16* __restrict__ hbuf, float* __restrict__ out,
        int* __restrict__ ctr) {    // ctr[1]=w2done, ctr[2+mt]=stage1 tiles done
    __shared__ alignas(16) char sA[128 * 128];
    __shared__ alignas(16) char sB[128 * 128];
    int tid = threadIdx.x;

    for (int task = (int)blockIdx.x; task < NTASK; task += PERS) {
        if (task < NW2) {
            // ---- w2 f32 -> bf16 (same chunking as r13 tail path) ----
            int n8 = E_ * D_ * H_ / 8;
            for (int i = task * 256 + tid; i < n8; i += NW2 * 256)
                *reinterpret_cast<bf16x8*>(w2b + (size_t)i * 8) = cvt8(w2 + (size_t)i * 8);
            __threadfence();
            __syncthreads();
            if (tid == 0) atomicAdd(&ctr[1], 1);
            __syncthreads();
        } else if (task < NW2 + NGEMM) {
            // ---- stage1 tile ----
            int f = task - NW2;                       // f % 8 == blockIdx % 8 (const)
            int swz = (f & 7) * (NGEMM / 8) + (f >> 3);
            int nt = swz % NT16, mt = swz / NT16;
            int e, row0, valid;
            bool ok = find_expert(counts, mt, e, row0, valid);
            if (ok) {
                gemm_body<D_, true>(sA, sB, tid, nt, e, row0, valid, xb, wb, hbuf, nullptr);
                __threadfence();                      // release h-tile
            }
            __syncthreads();
            if (ok && tid == 0) atomicAdd(&ctr[2 + mt], 1);
            __syncthreads();
        } else {
            // ---- stage2 tile (gated) ----
            int f = task - NW2 - NGEMM;
            int swz = (f & 7) * (NGEMM / 8) + (f >> 3);
            int nt = swz % NT16, mt = swz / NT16;
            int e, row0, valid;
            if (find_expert(counts, mt, e, row0, valid)) {
                if (tid == 0) {
                    while (atomicAdd(&ctr[1], 0) < NW2) __builtin_amdgcn_s_sleep(32);
                    while (atomicAdd(&ctr[2 + mt], 0) < NT16) __builtin_amdgcn_s_sleep(32);
                    __threadfence();                  // acquire
                }
                __syncthreads();
                gemm_body<H_, false>(sA, sB, tid, nt, e, row0, valid, hbuf, w2b, nullptr, out);
                __syncthreads();
            }
        }
    }
}

// ---------------- r13 fallback kernels (if ws lacks counter space) ----------------
template<int K_, bool FUSE>
__global__ __launch_bounds__(256, 4) void gemm128(
        const __bf16* __restrict__ A, const __bf16* __restrict__ Bw,
        const int* __restrict__ counts,
        __bf16* __restrict__ hout, float* __restrict__ fout,
        const float* __restrict__ cvt_src, __bf16* __restrict__ cvt_dst,
        int cvt_n8, int nGemm) {
    if ((int)blockIdx.x >= nGemm) {
        int nb = (int)gridDim.x - nGemm;
        int i = ((int)blockIdx.x - nGemm) * 256 + (int)threadIdx.x;
        int stride = nb * 256;
        for (; i < cvt_n8; i += stride)
            *reinterpret_cast<bf16x8*>(cvt_dst + (size_t)i * 8) = cvt8(cvt_src + (size_t)i * 8);
        return;
    }
    __shared__ alignas(16) char sA[128 * 128];
    __shared__ alignas(16) char sB[128 * 128];
    int tid = threadIdx.x;
    int f = (int)blockIdx.x;
    int swz = (f & 7) * (NGEMM / 8) + (f >> 3);
    int nt = swz % NT16, mt = swz / NT16;
    int e, row0, valid;
    if (!find_expert(counts, mt, e, row0, valid)) return;
    gemm_body<K_, FUSE>(sA, sB, tid, nt, e, row0, valid, A, Bw, hout, fout);
}

// ---------------- fused prep: cvt_x + interleave_w1w3 (r13 verbatim) ----------------
__global__ __launch_bounds__(256) void prep(const float* __restrict__ x,
                                            __bf16* __restrict__ xb,
                                            const float* __restrict__ w1,
                                            const float* __restrict__ w3,
                                            __bf16* __restrict__ wb) {
    int bid = blockIdx.x;
    if (bid < 2048) {
        int n8 = T_ * D_ / 8;
        int i = bid * 256 + threadIdx.x, stride = 2048 * 256;
        for (; i < n8; i += stride)
            *reinterpret_cast<bf16x8*>(xb + (size_t)i * 8) = cvt8(x + (size_t)i * 8);
    } else {
        int R = (bid - 2048) & 2047, e = (bid - 2048) >> 11;
        int g = R >> 5, r5 = R & 31;
        const float* src = (r5 < 16 ? w1 : w3)
                         + ((size_t)e * H_ + g * 16 + (r5 & 15)) * D_;
        __bf16* dst = wb + ((size_t)e * 2048 + R) * D_;
        int d = threadIdx.x * 8;
        *reinterpret_cast<bf16x8*>(dst + d) = cvt8(src + d);
    }
}

extern "C" void kernel_launch(void* const* d_in, const int* in_sizes, int n_in,
                              void* d_out, int out_size, void* d_ws, size_t ws_size,
                              hipStream_t stream) {
    const float* x      = (const float*)d_in[0];
    const float* w1     = (const float*)d_in[1];
    const float* w2     = (const float*)d_in[2];
    const float* w3     = (const float*)d_in[3];
    const int*   counts = (const int*)d_in[4];
    float* out = (float*)d_out;

    const size_t XB  = (size_t)T_ * D_ * 2;           // x bf16         67.1 MB
    const size_t HB  = (size_t)T_ * H_ * 2;           // h bf16         33.6 MB
    const size_t WIB = (size_t)E_ * 2 * H_ * D_ * 2;  // wb interleaved 67.1 MB
    const size_t W2B = (size_t)E_ * D_ * H_ * 2;      // w2 bf16        33.6 MB
    const size_t CTRO = XB + HB + WIB + W2B;          // counters offset

    char* ws = (char*)d_ws;
    __bf16* xb   = (__bf16*)(ws);
    __bf16* hbuf = (__bf16*)(ws + XB);
    __bf16* wb   = (__bf16*)(ws + XB + HB);
    __bf16* w2b  = (__bf16*)(ws + XB + HB + WIB);
    int* ctr     = (int*)(ws + CTRO);

    // prep: cvt x + interleave w1/w3 (one kernel, 18432 blocks)
    prep<<<2048 + E_ * 2048, 256, 0, stream>>>(x, xb, w1, w3, wb);

    if (ws_size >= CTRO + 1024) {
        hipMemsetAsync(ctr, 0, 1024, stream);
        ffn_fused<<<PERS, 256, 0, stream>>>(xb, wb, w2b, w2, counts, hbuf, out, ctr);
    } else {
        // r13-verified fallback: 3 launches
        gemm128<D_, true ><<<NGEMM + 512, 256, 0, stream>>>(
            xb, wb, counts, hbuf, nullptr, w2, w2b, E_ * D_ * H_ / 8, NGEMM);
        gemm128<H_, false><<<NGEMM, 256, 0, stream>>>(
            hbuf, w2b, counts, nullptr, out, nullptr, nullptr, 0, NGEMM);
    }
}

// Round 15
// 327.962 us; speedup vs baseline: 2.4361x; 2.4361x over previous
//
#include <hip/hip_runtime.h>
#include <hip/hip_bf16.h>
#include <math.h>

// Problem constants (fixed by reference)
constexpr int T_ = 16384;
constexpr int D_ = 2048;   // hidden
constexpr int H_ = 1024;   // intermediate
constexpr int E_ = 8;

constexpr int BM = 128, BK = 64;
constexpr int MT128 = T_ / 128 + E_;    // 136 worst-case m-tiles
constexpr int NT16  = 16;               // n-tiles (N = 2048 / 128), both stages
constexpr int NGEMM = MT128 * NT16;     // 2176, % 8 == 0

typedef __bf16 bf16x8 __attribute__((ext_vector_type(8)));
typedef float  f32x4  __attribute__((ext_vector_type(4)));

__device__ __forceinline__ int imin(int a, int b) { return a < b ? a : b; }

__device__ __forceinline__ bf16x8 cvt8(const float* p) {
    float4 u = *reinterpret_cast<const float4*>(p);
    float4 v = *reinterpret_cast<const float4*>(p + 4);
    bf16x8 r;
    r[0] = (__bf16)u.x; r[1] = (__bf16)u.y; r[2] = (__bf16)u.z; r[3] = (__bf16)u.w;
    r[4] = (__bf16)v.x; r[5] = (__bf16)v.y; r[6] = (__bf16)v.z; r[7] = (__bf16)v.w;
    return r;
}

// ---- 128x64 bf16 tile in LDS: 128B-pitch rows, XOR swizzle ((row&7)<<4).
// Measured SQ_LDS_BANK_CONFLICT == 0 (rounds 1-2, 9, 10, 13). VERBATIM.
__device__ __forceinline__ bf16x8 ld_lds8(const char* lds, int row, int kbyte) {
    int byte = row * 128 + (kbyte ^ ((row & 7) << 4));
    return *reinterpret_cast<const bf16x8*>(lds + byte);
}

// stage a 128x64 bf16 tile -> LDS via global_load_lds w=16, source pre-swizzled
// (VERBATIM round-13; 4 glds/thread, 16 chunks of 1KB).
template<int K_>
__device__ __forceinline__ void stage_glds(char* lds, const __bf16* __restrict__ src,
                                           int valid, int tid) {
    int wave = tid >> 6, l = tid & 63;
#pragma unroll
    for (int i = 0; i < 4; ++i) {
        int chunk = wave * 4 + i;            // 0..15, 1KB each
        int row = chunk * 8 + (l >> 3);      // LDS dest row (lane-implicit)
        int rc = imin(row, valid - 1);       // clamp source row for partial tiles
        int colb = ((l & 7) * 16) ^ ((row & 7) << 4);   // pre-swizzled source col
        const char* gp = reinterpret_cast<const char*>(src)
                       + (size_t)rc * (K_ * 2) + colb;
        __builtin_amdgcn_global_load_lds(
            (const __attribute__((address_space(1))) void*)gp,
            (__attribute__((address_space(3))) void*)(lds + chunk * 1024), 16, 0, 0);
    }
}

// expert lookup for BM=128 tiles (round-1 verbatim)
__device__ __forceinline__ bool find_expert(const int* __restrict__ counts, int mt,
                                            int& e, int& row0, int& valid) {
    int macc = 0, start = 0;
    e = -1;
    for (int i = 0; i < E_; ++i) {
        int c = counts[i];
        int t = (c + BM - 1) >> 7;
        if (e < 0 && mt < macc + t) {
            int lm = mt - macc;
            e = i; row0 = start + lm * BM; valid = imin(BM, c - lm * BM);
        }
        macc += t; start += c;
    }
    return e >= 0;
}

// =============== m97-structure 128x128 grouped GEMM, 4 blocks/CU ===============
// 256 threads (2x2 waves, 64x64/wave = acc[4][4], 64 VGPR); BK=64; single-buffered
// 32KB LDS; 2-barrier loop. Co-residency (~3-4 blocks/CU) provides stall hiding
// (m114). NOTE r12 lesson: (256,5) cuts VGPR to 48 -> acc spills -> 4x slower.
// NOTE r14 lesson: persistent producer/consumer fusion spins (static map, no
// stealing) -> 2.3x slower. This 3-launch structure is the verified optimum.
// Block order: XCD-chunked, nt-fastest (round-10, FETCH ~= compulsory).
// Tail blocks (blockIdx >= nGemm) do the w2 f32->bf16 conversion.
template<int K_, bool FUSE>
__global__ __launch_bounds__(256, 4) void gemm128(
        const __bf16* __restrict__ A, const __bf16* __restrict__ Bw,
        const int* __restrict__ counts,
        __bf16* __restrict__ hout, float* __restrict__ fout,
        const float* __restrict__ cvt_src, __bf16* __restrict__ cvt_dst,
        int cvt_n8, int nGemm) {
    if ((int)blockIdx.x >= nGemm) {
        int nb = (int)gridDim.x - nGemm;
        int i = ((int)blockIdx.x - nGemm) * 256 + (int)threadIdx.x;
        int stride = nb * 256;
        for (; i < cvt_n8; i += stride)
            *reinterpret_cast<bf16x8*>(cvt_dst + (size_t)i * 8) = cvt8(cvt_src + (size_t)i * 8);
        return;
    }
    __shared__ alignas(16) char sA[128 * 128];   // 16KB
    __shared__ alignas(16) char sB[128 * 128];   // 16KB

    int tid = threadIdx.x;
    // XCD-bijective chunked mapping, nt-fastest (nGemm = 2176, % 8 == 0)
    int f = (int)blockIdx.x;
    int swz = (f & 7) * (NGEMM / 8) + (f >> 3);
    int nt = swz % NT16, mt = swz / NT16;

    int e, row0, valid;
    if (!find_expert(counts, mt, e, row0, valid)) return;

    int wid = tid >> 6, lane = tid & 63;
    int wr = wid >> 1, wc = wid & 1;          // 2M x 2N
    int frow = lane & 15, fkb = (lane >> 4) * 16;

    const __bf16* Ab = A  + (size_t)row0 * K_;
    const __bf16* Bb = Bw + (size_t)e * 2048 * K_ + (size_t)(nt * 128) * K_;

    f32x4 acc[4][4] = {};

    for (int k0 = 0; k0 < K_; k0 += BK) {
        stage_glds<K_>(sA, Ab + k0, valid, tid);
        stage_glds<K_>(sB, Bb + k0, 128, tid);
        __syncthreads();
#pragma unroll
        for (int kk = 0; kk < BK; kk += 32) {
            int kb = kk * 2 + fkb;
            bf16x8 a[4], b[4];
#pragma unroll
            for (int m = 0; m < 4; ++m) a[m] = ld_lds8(sA, wr * 64 + m * 16 + frow, kb);
#pragma unroll
            for (int n = 0; n < 4; ++n) b[n] = ld_lds8(sB, wc * 64 + n * 16 + frow, kb);
#pragma unroll
            for (int m = 0; m < 4; ++m)
#pragma unroll
                for (int n = 0; n < 4; ++n)
                    acc[m][n] = __builtin_amdgcn_mfma_f32_16x16x32_bf16(a[m], b[n], acc[m][n], 0, 0, 0);
        }
        __syncthreads();
    }

    // ---- epilogue (verified) ----
    int q = lane >> 4;
#pragma unroll
    for (int m = 0; m < 4; ++m)
#pragma unroll
        for (int j = 0; j < 4; ++j) {
            int lrow = wr * 64 + m * 16 + q * 4 + j;
            if (lrow < valid) {
                size_t rg = (size_t)(row0 + lrow);
                if (FUSE) {
                    // wb rows interleaved in 32-row groups (16 w1 + 16 w3):
                    // n even -> w1 (c1), n odd -> w3 (c3), same h column.
#pragma unroll
                    for (int p = 0; p < 2; ++p) {
                        float c1 = acc[m][2 * p][j], c3 = acc[m][2 * p + 1][j];
                        float inner = 0.7978845608028654f * (c1 + 0.044715f * c1 * c1 * c1);
                        float g = 0.5f * c1 * (1.0f + tanhf(inner));
                        int col = nt * 64 + wc * 32 + p * 16 + frow;
                        hout[rg * H_ + col] = (__bf16)(g * c3);
                    }
                } else {
#pragma unroll
                    for (int n = 0; n < 4; ++n) {
                        int col = nt * 128 + wc * 64 + n * 16 + frow;
                        fout[rg * D_ + col] = acc[m][n][j];
                    }
                }
            }
        }
}

// ---------------- fused prep: cvt_x + interleave_w1w3 (round-10 verbatim) ----------------
__global__ __launch_bounds__(256) void prep(const float* __restrict__ x,
                                            __bf16* __restrict__ xb,
                                            const float* __restrict__ w1,
                                            const float* __restrict__ w3,
                                            __bf16* __restrict__ wb) {
    int bid = blockIdx.x;
    if (bid < 2048) {
        int n8 = T_ * D_ / 8;
        int i = bid * 256 + threadIdx.x, stride = 2048 * 256;
        for (; i < n8; i += stride)
            *reinterpret_cast<bf16x8*>(xb + (size_t)i * 8) = cvt8(x + (size_t)i * 8);
    } else {
        int R = (bid - 2048) & 2047, e = (bid - 2048) >> 11;
        int g = R >> 5, r5 = R & 31;
        const float* src = (r5 < 16 ? w1 : w3)
                         + ((size_t)e * H_ + g * 16 + (r5 & 15)) * D_;
        __bf16* dst = wb + ((size_t)e * 2048 + R) * D_;
        int d = threadIdx.x * 8;
        *reinterpret_cast<bf16x8*>(dst + d) = cvt8(src + d);
    }
}

extern "C" void kernel_launch(void* const* d_in, const int* in_sizes, int n_in,
                              void* d_out, int out_size, void* d_ws, size_t ws_size,
                              hipStream_t stream) {
    const float* x      = (const float*)d_in[0];
    const float* w1     = (const float*)d_in[1];
    const float* w2     = (const float*)d_in[2];
    const float* w3     = (const float*)d_in[3];
    const int*   counts = (const int*)d_in[4];
    float* out = (float*)d_out;

    const size_t XB  = (size_t)T_ * D_ * 2;           // x bf16         67.1 MB
    const size_t HB  = (size_t)T_ * H_ * 2;           // h bf16         33.6 MB
    const size_t WIB = (size_t)E_ * 2 * H_ * D_ * 2;  // wb interleaved 67.1 MB

    char* ws = (char*)d_ws;
    __bf16* xb   = (__bf16*)(ws);
    __bf16* hbuf = (__bf16*)(ws + XB);
    __bf16* wb   = (__bf16*)(ws + XB + HB);
    __bf16* w2b  = (__bf16*)(ws + XB + HB + WIB);
    (void)ws_size;

    // prep: cvt x + interleave w1/w3 (one kernel, 18432 blocks)
    prep<<<2048 + E_ * 2048, 256, 0, stream>>>(x, xb, w1, w3, wb);

    // stage1: single GEMM vs interleaved wb (N=2048, K=2048), fused gelu*mul;
    // + 512 tail blocks converting w2 (fills stage1's drain-out idle CUs)
    gemm128<D_, true ><<<NGEMM + 512, 256, 0, stream>>>(
        xb, wb, counts, hbuf, nullptr, w2, w2b, E_ * D_ * H_ / 8, NGEMM);

    // stage2: out = h @ w2^T (N=2048, K=1024)
    gemm128<H_, false><<<NGEMM, 256, 0, stream>>>(
        hbuf, w2b, counts, nullptr, out, nullptr, nullptr, 0, NGEMM);
}